// Round 1
// baseline (415.948 us; speedup 1.0000x reference)
//
#include <hip/hip_runtime.h>

// Quantize 8192x8192 fp32 -> fp8_e5m2 (round-tripped to fp32) with a
// power-of-two scale per 128x128 tile. MAX_EXP = 1.
//
// d_in[0]: x, fp32, 8192*8192
// d_out  : xq fp32 [8192*8192] followed by scale fp32 [64*64]
//
// Strategy: one 512-thread block per tile. Each thread holds 32 floats
// (8 x float4) in registers, computes local absmax, block-reduces, then
// quantizes from registers. x is read exactly once -> ~537 MB total traffic.

#define N        8192
#define TILE     128
#define TN       (N / TILE)          // 64 tiles per dim
#define TPB      512
#define VEC      4
#define PER_T    (TILE * TILE / TPB) // 32 floats / thread
#define ITERS    (PER_T / VEC)       // 8 float4 / thread

typedef float v2f __attribute__((ext_vector_type(2)));

__global__ __launch_bounds__(TPB) void quant_e5m2_tile_kernel(
    const float* __restrict__ x,
    float* __restrict__ xq,
    float* __restrict__ scale_out)
{
    const int tile = blockIdx.x;
    const int tr = tile / TN;
    const int tc = tile - tr * TN;
    const int tid = threadIdx.x;

    const float* __restrict__ tbase = x  + (size_t)tr * TILE * N + (size_t)tc * TILE;
    float* __restrict__       obase = xq + (size_t)tr * TILE * N + (size_t)tc * TILE;

    // ---- load tile into registers, tracking local absmax ----
    float4 v[ITERS];
    float amax = 0.0f;
#pragma unroll
    for (int i = 0; i < ITERS; ++i) {
        const int lin = (i * TPB + tid) * VEC;   // element offset within tile
        const int row = lin >> 7;                // / 128
        const int col = lin & (TILE - 1);
        v[i] = *reinterpret_cast<const float4*>(tbase + (size_t)row * N + col);
        amax = fmaxf(amax,
               fmaxf(fmaxf(fabsf(v[i].x), fabsf(v[i].y)),
                     fmaxf(fabsf(v[i].z), fabsf(v[i].w))));
    }

    // ---- wave (64-lane) max reduce ----
#pragma unroll
    for (int m = 1; m < 64; m <<= 1)
        amax = fmaxf(amax, __shfl_xor(amax, m, 64));

    // ---- cross-wave reduce via tiny LDS ----
    __shared__ float smax[TPB / 64];
    const int wid = tid >> 6;
    if ((tid & 63) == 0) smax[wid] = amax;
    __syncthreads();
    amax = smax[0];
#pragma unroll
    for (int w = 1; w < TPB / 64; ++w)
        amax = fmaxf(amax, smax[w]);

    // ---- e = ceil(log2(amax)) exactly (amax==0 -> e=0, matching reference) ----
    int e = 0;
    if (amax > 0.0f) {
        int ex;
        float m = frexpf(amax, &ex);     // amax = m * 2^ex, m in [0.5,1)
        e = (m == 0.5f) ? ex - 1 : ex;   // exact ceil(log2)
    }
    const float inv = ldexpf(1.0f, 1 - e);   // 2^(MAX_EXP - e), exact

    // ---- quantize from registers: mul (exact), cvt->bf8 (RTNE), cvt back ----
#pragma unroll
    for (int i = 0; i < ITERS; ++i) {
        const int lin = (i * TPB + tid) * VEC;
        const int row = lin >> 7;
        const int col = lin & (TILE - 1);
        const float a = v[i].x * inv;
        const float b = v[i].y * inv;
        const float c = v[i].z * inv;
        const float d = v[i].w * inv;
        int pk = __builtin_amdgcn_cvt_pk_bf8_f32(a, b, 0, false);
        pk     = __builtin_amdgcn_cvt_pk_bf8_f32(c, d, pk, true);
        const v2f lo = __builtin_amdgcn_cvt_pk_f32_bf8(pk, false);
        const v2f hi = __builtin_amdgcn_cvt_pk_f32_bf8(pk, true);
        float4 o;
        o.x = lo.x; o.y = lo.y; o.z = hi.x; o.w = hi.y;
        *reinterpret_cast<float4*>(obase + (size_t)row * N + col) = o;
    }

    if (tid == 0)
        scale_out[tile] = ldexpf(1.0f, e - 1);   // 2^(e - MAX_EXP)
}

extern "C" void kernel_launch(void* const* d_in, const int* in_sizes, int n_in,
                              void* d_out, int out_size, void* d_ws, size_t ws_size,
                              hipStream_t stream) {
    const float* x = (const float*)d_in[0];
    float* xq        = (float*)d_out;
    float* scale_out = (float*)d_out + (size_t)N * N;

    quant_e5m2_tile_kernel<<<TN * TN, TPB, 0, stream>>>(x, xq, scale_out);
}

// Round 5
// 406.587 us; speedup vs baseline: 1.0230x; 1.0230x over previous
//
#include <hip/hip_runtime.h>

// Quantize 8192x8192 fp32 -> fp8_e5m2 (round-tripped to fp32) with a
// power-of-two scale per 128x128 tile. MAX_EXP = 1.
//
// d_in[0]: x, fp32, 8192*8192
// d_out  : xq fp32 [8192*8192] followed by scale fp32 [64*64]
//
// Round 4 (resubmit of R3; broker timeout, never ran): native ext_vector
// float4 (v4f) so the nontemporal builtins compile (HIP float4 is a
// class -> rejected). 1024 threads/block x 16 floats/thread in
// registers; nt loads/stores keep the 537 MB stream out of L2.

#define N        8192
#define TILE     128
#define TN       (N / TILE)          // 64 tiles per dim
#define TPB      1024
#define VEC      4
#define PER_T    (TILE * TILE / TPB) // 16 floats / thread
#define ITERS    (PER_T / VEC)       // 4 float4 / thread

typedef float v2f __attribute__((ext_vector_type(2)));
typedef float v4f __attribute__((ext_vector_type(4)));

__global__ __launch_bounds__(TPB) void quant_e5m2_tile_kernel(
    const float* __restrict__ x,
    float* __restrict__ xq,
    float* __restrict__ scale_out)
{
    const int tile = blockIdx.x;
    const int tr = tile >> 6;            // / TN
    const int tc = tile & (TN - 1);
    const int tid = threadIdx.x;

    const size_t base = (size_t)tr * TILE * N + (size_t)tc * TILE;
    const float* __restrict__ tbase = x  + base;
    float* __restrict__       obase = xq + base;

    // ---- load tile into registers, tracking local absmax ----
    v4f v[ITERS];
    float amax = 0.0f;
#pragma unroll
    for (int i = 0; i < ITERS; ++i) {
        const int lin = (i * TPB + tid) * VEC;   // element offset within tile
        const int row = lin >> 7;                // / 128
        const int col = lin & (TILE - 1);
        v[i] = __builtin_nontemporal_load(
                   reinterpret_cast<const v4f*>(tbase + (size_t)row * N + col));
        amax = fmaxf(amax,
               fmaxf(fmaxf(fabsf(v[i].x), fabsf(v[i].y)),
                     fmaxf(fabsf(v[i].z), fabsf(v[i].w))));
    }

    // ---- wave (64-lane) max reduce ----
#pragma unroll
    for (int m = 1; m < 64; m <<= 1)
        amax = fmaxf(amax, __shfl_xor(amax, m, 64));

    // ---- cross-wave reduce via tiny LDS ----
    __shared__ float smax[TPB / 64];
    if ((tid & 63) == 0) smax[tid >> 6] = amax;
    __syncthreads();
    amax = smax[0];
#pragma unroll
    for (int w = 1; w < TPB / 64; ++w)
        amax = fmaxf(amax, smax[w]);

    // ---- e = ceil(log2(amax)) exactly (amax==0 -> e=0, matching reference) ----
    int e = 0;
    if (amax > 0.0f) {
        int ex;
        float m = frexpf(amax, &ex);     // amax = m * 2^ex, m in [0.5,1)
        e = (m == 0.5f) ? ex - 1 : ex;   // exact ceil(log2)
    }
    const float inv = ldexpf(1.0f, 1 - e);   // 2^(MAX_EXP - e), exact

    // ---- quantize from registers: mul (exact), cvt->bf8 (RTNE), cvt back ----
#pragma unroll
    for (int i = 0; i < ITERS; ++i) {
        const int lin = (i * TPB + tid) * VEC;
        const int row = lin >> 7;
        const int col = lin & (TILE - 1);
        int pk = __builtin_amdgcn_cvt_pk_bf8_f32(v[i].x * inv, v[i].y * inv, 0, false);
        pk     = __builtin_amdgcn_cvt_pk_bf8_f32(v[i].z * inv, v[i].w * inv, pk, true);
        const v2f lo = __builtin_amdgcn_cvt_pk_f32_bf8(pk, false);
        const v2f hi = __builtin_amdgcn_cvt_pk_f32_bf8(pk, true);
        v4f o;
        o.x = lo.x; o.y = lo.y; o.z = hi.x; o.w = hi.y;
        __builtin_nontemporal_store(o,
            reinterpret_cast<v4f*>(obase + (size_t)row * N + col));
    }

    if (tid == 0)
        scale_out[tile] = ldexpf(1.0f, e - 1);   // 2^(e - MAX_EXP)
}

extern "C" void kernel_launch(void* const* d_in, const int* in_sizes, int n_in,
                              void* d_out, int out_size, void* d_ws, size_t ws_size,
                              hipStream_t stream) {
    const float* x = (const float*)d_in[0];
    float* xq        = (float*)d_out;
    float* scale_out = (float*)d_out + (size_t)N * N;

    quant_e5m2_tile_kernel<<<TN * TN, TPB, 0, stream>>>(x, xq, scale_out);
}